// Round 9
// baseline (317.127 us; speedup 1.0000x reference)
//
#include <hip/hip_runtime.h>

// Gated delta rule recurrence S_t = S_{t-1} @ A_t + B_t, outputs all S_t.
// T=128, B*H=64 chains, D=64. Two-level chunked scan, NC=16 chunks of CH=8.
//   K1 (fold): chunk summaries (PA,PB)           [1024 blocks x 7 steps]
//   K2 (scan): over 16 summaries -> chunk-end states into out [64 blocks]
//   K3 (scan): in-chunk recurrence -> remaining states        [1024 blocks]
// Split-bf16 MFMA (hi/lo, 3 products), transposed recurrence S^T <- A^T S^T.
// A tiles DMA'd HBM->LDS via global_load_lds (transpose+XOR-swizzle baked into
// the per-lane GLOBAL source address; LDS dest linear). bf16 split of A at
// consume time from fp32 LDS. r9 vs r8: the hand-counted vmcnt(4)+raw-barrier
// discipline is replaced by plain __syncthreads() (safe drain; loads are
// issued at step TOP so they arrive during compute - convoy still broken).

constexpr int kT = 128;
constexpr int kBH = 64;
constexpr int kD = 64;
constexpr int kTile = kD * kD;
constexpr int kNC = 16;
constexpr int kCH = 8;

typedef __attribute__((ext_vector_type(8))) short short8;
typedef __attribute__((ext_vector_type(4))) float f32x4;
using u32 = unsigned int;

union U8 { u32 u[4]; short8 s; };

__device__ __forceinline__ f32x4 mfma16(short8 a, short8 b, f32x4 c) {
  return __builtin_amdgcn_mfma_f32_16x16x32_bf16(a, b, c, 0, 0, 0);
}

// split 2 floats into packed hi/lo bf16 pairs (1 v_cvt_pk each + exact residual)
__device__ __forceinline__ void pk_split(float a, float b, u32& h, u32& l) {
  u32 hu;
  asm("v_cvt_pk_bf16_f32 %0, %1, %2" : "=v"(hu) : "v"(a), "v"(b));
  const float ra = a - __uint_as_float(hu << 16);
  const float rb = b - __uint_as_float(hu & 0xffff0000u);
  u32 lu;
  asm("v_cvt_pk_bf16_f32 %0, %1, %2" : "=v"(lu) : "v"(ra), "v"(rb));
  h = hu;
  l = lu;
}

// Build one K=32 B-operand fragment from two C/D tiles (X = tile 2ks, Y = 2ks+1).
__device__ __forceinline__ short8 gather_frag(u32 p01, u32 p23, u32 q01, u32 q23,
                                              int ad0, int ad1, bool lowh) {
  U8 r;
  int x, y;
  x = __builtin_amdgcn_ds_bpermute(ad0, (int)p01);
  y = __builtin_amdgcn_ds_bpermute(ad0, (int)q01);
  r.u[0] = (u32)(lowh ? x : y);
  x = __builtin_amdgcn_ds_bpermute(ad0, (int)p23);
  y = __builtin_amdgcn_ds_bpermute(ad0, (int)q23);
  r.u[1] = (u32)(lowh ? x : y);
  x = __builtin_amdgcn_ds_bpermute(ad1, (int)p01);
  y = __builtin_amdgcn_ds_bpermute(ad1, (int)q01);
  r.u[2] = (u32)(lowh ? x : y);
  x = __builtin_amdgcn_ds_bpermute(ad1, (int)p23);
  y = __builtin_amdgcn_ds_bpermute(ad1, (int)q23);
  r.u[3] = (u32)(lowh ? x : y);
  return r.s;
}

// Read one A-operand fragment (row, k0..k0+7) from swizzled fp32 LDS and
// split to hi/lo bf16. Swizzle: phys = row*64 + (k ^ ((row&7)<<2)).
__device__ __forceinline__ void read_afrag(const float* sAbuf, int row, int k0,
                                           short8& ah, short8& al) {
  const int m = (row & 7) << 2;
  const f32x4 x = *reinterpret_cast<const f32x4*>(&sAbuf[row * 64 + (k0 ^ m)]);
  const f32x4 y = *reinterpret_cast<const f32x4*>(&sAbuf[row * 64 + ((k0 + 4) ^ m)]);
  U8 h, l;
  u32 hu, lu;
  pk_split(x[0], x[1], hu, lu); h.u[0] = hu; l.u[0] = lu;
  pk_split(x[2], x[3], hu, lu); h.u[1] = hu; l.u[1] = lu;
  pk_split(y[0], y[1], hu, lu); h.u[2] = hu; l.u[2] = lu;
  pk_split(y[2], y[3], hu, lu); h.u[3] = hu; l.u[3] = lu;
  ah = h.s; al = l.s;
}

// Issue 16 global_load_lds (1 dword/lane) staging A tile (transposed+swizzled
// via the per-lane global source offset) into SBUF (linear LDS dest).
// Instruction n=w*16+it writes LDS row n; lane l supplies A[(l^((n&7)<<2))][n].
#define ISSUE_A(PTRA, SBUF)                                                   \
  do {                                                                        \
    const char* gb_ = (const char*)(PTRA);                                    \
    _Pragma("unroll") for (int it_ = 0; it_ < 16; ++it_) {                    \
      __builtin_amdgcn_global_load_lds(                                       \
          (const __attribute__((address_space(1))) u32*)(gb_ + aoff[it_]),    \
          (__attribute__((address_space(3))) u32*)&(SBUF)[(w * 16 + it_) * 64], \
          4, 0, 0);                                                           \
    }                                                                         \
    __builtin_amdgcn_sched_barrier(0);                                        \
  } while (0)

#define LOAD_B4(PTRB)                                                          \
  do {                                                                         \
    const float* Bt_ = (PTRB);                                                 \
    b0 = *reinterpret_cast<const f32x4*>(Bt_ + rowbase + 0 * 16 + q * 4);      \
    b1 = *reinterpret_cast<const f32x4*>(Bt_ + rowbase + 1 * 16 + q * 4);      \
    b2 = *reinterpret_cast<const f32x4*>(Bt_ + rowbase + 2 * 16 + q * 4);      \
    b3 = *reinterpret_cast<const f32x4*>(Bt_ + rowbase + 3 * 16 + q * 4);      \
  } while (0)

// ---------------- fold: (pa,pb) <- fold of nElem (A,B) elements ----------------
// step J: reads sA=SCUR (element J+1), issues element J+2 -> SNXT (if any),
// consumes b0..b3 (B element J+1), reissues B element J+2 (if any).
#define FOLD_STEP(J, SCUR, SNXT)                                              \
  do {                                                                        \
    const int j_ = (J);                                                       \
    const bool more_ = (j_ + 1 < nS);                                         \
    if (more_)                                                                \
      ISSUE_A(srcA + (size_t)(e0 + (long)(j_ + 2) * elemStride) * kTile, SNXT); \
    f32x4 npa[4], npb[4];                                                     \
    npb[0] = b0; npb[1] = b1; npb[2] = b2; npb[3] = b3;                       \
    _Pragma("unroll") for (int cm = 0; cm < 4; ++cm)                          \
        npa[cm] = (f32x4){0.f, 0.f, 0.f, 0.f};                                \
    if (more_)                                                                \
      LOAD_B4(srcB + (size_t)(e0 + (long)(j_ + 2) * elemStride) * kTile);     \
    _Pragma("unroll") for (int ks = 0; ks < 2; ++ks) {                        \
      u32 pa01h, pa01l, pa23h, pa23l, qa01h, qa01l, qa23h, qa23l;             \
      u32 pb01h, pb01l, pb23h, pb23l, qb01h, qb01l, qb23h, qb23l;             \
      pk_split(apa[2 * ks][0], apa[2 * ks][1], pa01h, pa01l);                 \
      pk_split(apa[2 * ks][2], apa[2 * ks][3], pa23h, pa23l);                 \
      pk_split(apa[2 * ks + 1][0], apa[2 * ks + 1][1], qa01h, qa01l);         \
      pk_split(apa[2 * ks + 1][2], apa[2 * ks + 1][3], qa23h, qa23l);         \
      pk_split(apb[2 * ks][0], apb[2 * ks][1], pb01h, pb01l);                 \
      pk_split(apb[2 * ks][2], apb[2 * ks][3], pb23h, pb23l);                 \
      pk_split(apb[2 * ks + 1][0], apb[2 * ks + 1][1], qb01h, qb01l);         \
      pk_split(apb[2 * ks + 1][2], apb[2 * ks + 1][3], qb23h, qb23l);         \
      const short8 bah = gather_frag(pa01h, pa23h, qa01h, qa23h, ad0, ad1, lowh); \
      const short8 bal = gather_frag(pa01l, pa23l, qa01l, qa23l, ad0, ad1, lowh); \
      const short8 bbh = gather_frag(pb01h, pb23h, qb01h, qb23h, ad0, ad1, lowh); \
      const short8 bbl = gather_frag(pb01l, pb23l, qb01l, qb23l, ad0, ad1, lowh); \
      _Pragma("unroll") for (int cm = 0; cm < 4; ++cm) {                      \
        short8 ah, al;                                                        \
        read_afrag(&(SCUR)[0], cm * 16 + l15, ks * 32 + q * 8, ah, al);       \
        npa[cm] = mfma16(ah, bah, npa[cm]);                                   \
        npa[cm] = mfma16(ah, bal, npa[cm]);                                   \
        npa[cm] = mfma16(al, bah, npa[cm]);                                   \
        npb[cm] = mfma16(ah, bbh, npb[cm]);                                   \
        npb[cm] = mfma16(ah, bbl, npb[cm]);                                   \
        npb[cm] = mfma16(al, bbh, npb[cm]);                                   \
      }                                                                       \
    }                                                                         \
    _Pragma("unroll") for (int cm = 0; cm < 4; ++cm) {                        \
      apa[cm] = npa[cm];                                                      \
      apb[cm] = npb[cm];                                                      \
    }                                                                         \
    if (more_) __syncthreads();                                               \
  } while (0)

__global__ __launch_bounds__(256, 4) void gdr_fold(
    const float* __restrict__ srcA, const float* __restrict__ srcB,
    float* __restrict__ dstA, float* __restrict__ dstB,
    int perChain, long chainBase, long idxBase, long elemStride, int nElem) {
  __shared__ float sA0[4096], sA1[4096];

  const int tid = threadIdx.x;
  const int lane = tid & 63, w = tid >> 6;
  const int q = lane >> 4, l15 = lane & 15;
  const int bh = blockIdx.x / perChain, id = blockIdx.x % perChain;
  const long e0 = (long)bh * chainBase + (long)id * idxBase;
  const int rowbase = (w * 16 + l15) * 64;
  const int ad0 = (l15 + ((lane >> 4) & 1) * 32) * 4;
  const int ad1 = ad0 + 64;
  const bool lowh = lane < 32;
  const int nS = nElem - 1;

  // per-lane byte offsets for the transpose+swizzle staging
  int aoff[16];
#pragma unroll
  for (int it = 0; it < 16; ++it) {
    const int n = w * 16 + it;
    aoff[it] = (((lane ^ ((n & 7) << 2)) << 6) + n) * 4;
  }

  f32x4 apa[4], apb[4];
  {
    const float* At = srcA + (size_t)e0 * kTile;
    const float* Bt = srcB + (size_t)e0 * kTile;
#pragma unroll
    for (int cm = 0; cm < 4; ++cm) {
      apa[cm] = *reinterpret_cast<const f32x4*>(At + rowbase + cm * 16 + q * 4);
      apb[cm] = *reinterpret_cast<const f32x4*>(Bt + rowbase + cm * 16 + q * 4);
    }
  }

  f32x4 b0, b1, b2, b3;
  // prologue: stage element 1 -> sA0; preload B element 1.
  ISSUE_A(srcA + (size_t)(e0 + elemStride) * kTile, sA0);
  LOAD_B4(srcB + (size_t)(e0 + elemStride) * kTile);
  __syncthreads();

  int j = 0;
  while (true) {
    FOLD_STEP(j, sA0, sA1);
    if (++j >= nS) break;
    FOLD_STEP(j, sA1, sA0);
    if (++j >= nS) break;
  }

  float* pao = dstA + (size_t)blockIdx.x * kTile;
  float* pbo = dstB + (size_t)blockIdx.x * kTile;
#pragma unroll
  for (int cm = 0; cm < 4; ++cm) {
    *reinterpret_cast<f32x4*>(pao + rowbase + cm * 16 + q * 4) = apa[cm];
    *reinterpret_cast<f32x4*>(pbo + rowbase + cm * 16 + q * 4) = apb[cm];
  }
}

// ---------------- scan: apply nSteps elements, write states into out ----------------
// step I: reads sA=SCUR (element I), issues element I+1 -> SNXT (if any),
// consumes b0..b3 (B element I), reissues B element I+1 (if any).
#define SCAN_STEP(I, SCUR, SNXT)                                              \
  do {                                                                        \
    const int i_ = (I);                                                       \
    const bool more_ = (i_ + 1 < nSteps);                                     \
    if (more_)                                                                \
      ISSUE_A(srcA + (size_t)(e0 + (long)(i_ + 1) * elemStride) * kTile, SNXT); \
    f32x4 nacc[4];                                                            \
    nacc[0] = b0; nacc[1] = b1; nacc[2] = b2; nacc[3] = b3;                   \
    if (more_)                                                                \
      LOAD_B4(srcB + (size_t)(e0 + (long)(i_ + 1) * elemStride) * kTile);     \
    _Pragma("unroll") for (int ks = 0; ks < 2; ++ks) {                        \
      u32 p01h, p01l, p23h, p23l, q01h, q01l, q23h, q23l;                     \
      pk_split(acc[2 * ks][0], acc[2 * ks][1], p01h, p01l);                   \
      pk_split(acc[2 * ks][2], acc[2 * ks][3], p23h, p23l);                   \
      pk_split(acc[2 * ks + 1][0], acc[2 * ks + 1][1], q01h, q01l);           \
      pk_split(acc[2 * ks + 1][2], acc[2 * ks + 1][3], q23h, q23l);           \
      const short8 bfh = gather_frag(p01h, p23h, q01h, q23h, ad0, ad1, lowh); \
      const short8 bfl = gather_frag(p01l, p23l, q01l, q23l, ad0, ad1, lowh); \
      _Pragma("unroll") for (int cm = 0; cm < 4; ++cm) {                      \
        short8 ah, al;                                                        \
        read_afrag(&(SCUR)[0], cm * 16 + l15, ks * 32 + q * 8, ah, al);       \
        nacc[cm] = mfma16(ah, bfh, nacc[cm]);                                 \
        nacc[cm] = mfma16(ah, bfl, nacc[cm]);                                 \
        nacc[cm] = mfma16(al, bfh, nacc[cm]);                                 \
      }                                                                       \
    }                                                                         \
    const int t_ = tBase + (i_ + 1) * tStep - 1;                              \
    float* o_ = out + ((size_t)t_ * kBH + bh) * kTile;                        \
    _Pragma("unroll") for (int cm = 0; cm < 4; ++cm) {                        \
      *reinterpret_cast<f32x4*>(o_ + rowbase + cm * 16 + q * 4) = nacc[cm];   \
      acc[cm] = nacc[cm];                                                     \
    }                                                                         \
    if (more_) __syncthreads();                                               \
  } while (0)

__global__ __launch_bounds__(256, 4) void gdr_scan(
    const float* __restrict__ srcA, const float* __restrict__ srcB,
    const float* __restrict__ S0, float* __restrict__ out,
    int perChain, long chainBase, long idxBase, long elemStride,
    int nSteps, int tbMul, int tStep) {
  __shared__ float sA0[4096], sA1[4096];

  const int tid = threadIdx.x;
  const int lane = tid & 63, w = tid >> 6;
  const int q = lane >> 4, l15 = lane & 15;
  const int bh = blockIdx.x / perChain, id = blockIdx.x % perChain;
  const long e0 = (long)bh * chainBase + (long)id * idxBase;
  const int tBase = id * tbMul;
  const int rowbase = (w * 16 + l15) * 64;
  const int ad0 = (l15 + ((lane >> 4) & 1) * 32) * 4;
  const int ad1 = ad0 + 64;
  const bool lowh = lane < 32;

  int aoff[16];
#pragma unroll
  for (int it = 0; it < 16; ++it) {
    const int n = w * 16 + it;
    aoff[it] = (((lane ^ ((n & 7) << 2)) << 6) + n) * 4;
  }

  f32x4 acc[4];
  {
    const float* Sb = (tBase == 0) ? (S0 + (size_t)bh * kTile)
                                   : (out + ((size_t)(tBase - 1) * kBH + bh) * kTile);
#pragma unroll
    for (int cm = 0; cm < 4; ++cm)
      acc[cm] = *reinterpret_cast<const f32x4*>(Sb + rowbase + cm * 16 + q * 4);
  }

  f32x4 b0, b1, b2, b3;
  // prologue: stage element 0 -> sA0; preload B element 0.
  ISSUE_A(srcA + (size_t)e0 * kTile, sA0);
  LOAD_B4(srcB + (size_t)e0 * kTile);
  __syncthreads();

  int i = 0;
  while (true) {
    SCAN_STEP(i, sA0, sA1);
    if (++i >= nSteps) break;
    SCAN_STEP(i, sA1, sA0);
    if (++i >= nSteps) break;
  }
}

extern "C" void kernel_launch(void* const* d_in, const int* in_sizes, int n_in,
                              void* d_out, int out_size, void* d_ws, size_t ws_size,
                              hipStream_t stream) {
  const float* A  = (const float*)d_in[0];
  const float* Bm = (const float*)d_in[1];
  const float* S0 = (const float*)d_in[2];
  float* out = (float*)d_out;

  // workspace: PA[64*16], PB[64*16] tiles of 16 KB = 32 MB
  float* PA = (float*)d_ws;
  float* PB = PA + (size_t)kBH * kNC * kTile;

  // K1: chunk summaries. elements (ck*8+i)*64+bh, i=0..7
  gdr_fold<<<dim3(kBH * kNC), dim3(256), 0, stream>>>(
      A, Bm, PA, PB, kNC, 1L, (long)kCH * kBH, (long)kBH, kCH);
  // K2: scan 16 summaries (tiles bh*16+i); writes t = (i+1)*8-1 (7,15,...,127)
  gdr_scan<<<dim3(kBH), dim3(256), 0, stream>>>(
      PA, PB, S0, out, 1, (long)kNC, 0L, 1L, kNC, 0, kCH);
  // K3: in-chunk recurrence; elements (ck*8+i)*64+bh, start out[ck*8-1]/S0,
  //     writes t = ck*8+i for i=0..6
  gdr_scan<<<dim3(kBH * kNC), dim3(256), 0, stream>>>(
      A, Bm, S0, out, kNC, 1L, (long)kCH * kBH, (long)kBH, kCH - 1, kCH, 1);
}

// Round 10
// 161.189 us; speedup vs baseline: 1.9674x; 1.9674x over previous
//
#include <hip/hip_runtime.h>

// Gated delta rule recurrence S_t = S_{t-1} @ A_t + B_t, outputs all S_t.
// T=128, B*H=64 chains, D=64. Two-level chunked scan, NC=16 chunks of CH=8.
//   K1 (fold): chunk summaries (PA,PB)           [1024 blocks x 7 steps]
//   K2 (scan): over 16 summaries -> chunk-end states into out [64 blocks]
//   K3 (scan): in-chunk recurrence -> remaining states        [1024 blocks]
// Split-bf16 MFMA (hi/lo, 3 products), transposed recurrence S^T <- A^T S^T.
// r10: A tiles DMA'd HBM->LDS with LINEAR COALESCED global_load_lds width=16
// (1KB contiguous per inst, 4 insts/wave, zero registers, no offset table).
// LDS holds A row-major; the A^T fragment read happens at consume time as
// stride-64 scalar ds_reads (4-way bank aliasing, ~1.58x — acceptable).
// B stays in 16 registers (4 coalesced dwordx4). Loads issued at step TOP,
// plain __syncthreads() drain at step end (safe; latency hidden by compute).
// amdgpu_waves_per_eu(4,4) forces the 128-VGPR budget (no spill heuristic).

constexpr int kT = 128;
constexpr int kBH = 64;
constexpr int kD = 64;
constexpr int kTile = kD * kD;
constexpr int kNC = 16;
constexpr int kCH = 8;

typedef __attribute__((ext_vector_type(8))) short short8;
typedef __attribute__((ext_vector_type(4))) float f32x4;
using u32 = unsigned int;

union U8 { u32 u[4]; short8 s; };

__device__ __forceinline__ f32x4 mfma16(short8 a, short8 b, f32x4 c) {
  return __builtin_amdgcn_mfma_f32_16x16x32_bf16(a, b, c, 0, 0, 0);
}

// split 2 floats into packed hi/lo bf16 pairs (1 v_cvt_pk each + exact residual)
__device__ __forceinline__ void pk_split(float a, float b, u32& h, u32& l) {
  u32 hu;
  asm("v_cvt_pk_bf16_f32 %0, %1, %2" : "=v"(hu) : "v"(a), "v"(b));
  const float ra = a - __uint_as_float(hu << 16);
  const float rb = b - __uint_as_float(hu & 0xffff0000u);
  u32 lu;
  asm("v_cvt_pk_bf16_f32 %0, %1, %2" : "=v"(lu) : "v"(ra), "v"(rb));
  h = hu;
  l = lu;
}

// Build one K=32 B-operand fragment from two C/D tiles (X = tile 2ks, Y = 2ks+1).
__device__ __forceinline__ short8 gather_frag(u32 p01, u32 p23, u32 q01, u32 q23,
                                              int ad0, int ad1, bool lowh) {
  U8 r;
  int x, y;
  x = __builtin_amdgcn_ds_bpermute(ad0, (int)p01);
  y = __builtin_amdgcn_ds_bpermute(ad0, (int)q01);
  r.u[0] = (u32)(lowh ? x : y);
  x = __builtin_amdgcn_ds_bpermute(ad0, (int)p23);
  y = __builtin_amdgcn_ds_bpermute(ad0, (int)q23);
  r.u[1] = (u32)(lowh ? x : y);
  x = __builtin_amdgcn_ds_bpermute(ad1, (int)p01);
  y = __builtin_amdgcn_ds_bpermute(ad1, (int)q01);
  r.u[2] = (u32)(lowh ? x : y);
  x = __builtin_amdgcn_ds_bpermute(ad1, (int)p23);
  y = __builtin_amdgcn_ds_bpermute(ad1, (int)q23);
  r.u[3] = (u32)(lowh ? x : y);
  return r.s;
}

// Read A^T fragment (rows = A cols) from LINEAR row-major fp32 A tile in LDS:
// need A[k0+j][row], j=0..7 -> LDS dword (k0+j)*64 + row. Compiler pairs the
// constant-offset scalar reads into ds_read2_b32.
__device__ __forceinline__ void read_afragT(const float* sAbuf, int row, int k0,
                                            short8& ah, short8& al) {
  const float* base = sAbuf + k0 * 64 + row;
  float d0 = base[0], d1 = base[64], d2 = base[128], d3 = base[192];
  float d4 = base[256], d5 = base[320], d6 = base[384], d7 = base[448];
  U8 h, l;
  u32 hu, lu;
  pk_split(d0, d1, hu, lu); h.u[0] = hu; l.u[0] = lu;
  pk_split(d2, d3, hu, lu); h.u[1] = hu; l.u[1] = lu;
  pk_split(d4, d5, hu, lu); h.u[2] = hu; l.u[2] = lu;
  pk_split(d6, d7, hu, lu); h.u[3] = hu; l.u[3] = lu;
  ah = h.s; al = l.s;
}

// Issue 4 coalesced global_load_lds (width 16) staging this wave's 4KB quarter
// of the A tile, LINEAR row-major (src 1KB contiguous per inst).
#define ISSUE_A(PTRA, SBUF)                                                     \
  do {                                                                          \
    const float* gp_ = (PTRA);                                                  \
    _Pragma("unroll") for (int it_ = 0; it_ < 4; ++it_) {                       \
      const int off_ = (w * 4 + it_) * 256;                                     \
      __builtin_amdgcn_global_load_lds(                                         \
          (const __attribute__((address_space(1))) u32*)(gp_ + off_ + lane * 4),\
          (__attribute__((address_space(3))) u32*)&(SBUF)[off_],                \
          16, 0, 0);                                                            \
    }                                                                           \
  } while (0)

#define LOAD_B4(PTRB)                                                          \
  do {                                                                         \
    const float* Bt_ = (PTRB);                                                 \
    b0 = *reinterpret_cast<const f32x4*>(Bt_ + rowbase + 0 * 16 + q * 4);      \
    b1 = *reinterpret_cast<const f32x4*>(Bt_ + rowbase + 1 * 16 + q * 4);      \
    b2 = *reinterpret_cast<const f32x4*>(Bt_ + rowbase + 2 * 16 + q * 4);      \
    b3 = *reinterpret_cast<const f32x4*>(Bt_ + rowbase + 3 * 16 + q * 4);      \
  } while (0)

// ---------------- fold: (pa,pb) <- fold of nElem (A,B) elements ----------------
// step J: issues element J+2 -> SNXT + B(J+2) at TOP, consumes b0..b3
// (B element J+1), computes with sA=SCUR (element J+1), drain barrier.
#define FOLD_STEP(J, SCUR, SNXT)                                              \
  do {                                                                        \
    const int j_ = (J);                                                       \
    const bool more_ = (j_ + 1 < nS);                                         \
    f32x4 npa[4], npb[4];                                                     \
    npb[0] = b0; npb[1] = b1; npb[2] = b2; npb[3] = b3;                       \
    _Pragma("unroll") for (int cm = 0; cm < 4; ++cm)                          \
        npa[cm] = (f32x4){0.f, 0.f, 0.f, 0.f};                                \
    if (more_) {                                                              \
      ISSUE_A(srcA + (size_t)(e0 + (long)(j_ + 2) * elemStride) * kTile, SNXT); \
      LOAD_B4(srcB + (size_t)(e0 + (long)(j_ + 2) * elemStride) * kTile);     \
      __builtin_amdgcn_sched_barrier(0);                                      \
    }                                                                         \
    _Pragma("unroll") for (int ks = 0; ks < 2; ++ks) {                        \
      u32 pa01h, pa01l, pa23h, pa23l, qa01h, qa01l, qa23h, qa23l;             \
      u32 pb01h, pb01l, pb23h, pb23l, qb01h, qb01l, qb23h, qb23l;             \
      pk_split(apa[2 * ks][0], apa[2 * ks][1], pa01h, pa01l);                 \
      pk_split(apa[2 * ks][2], apa[2 * ks][3], pa23h, pa23l);                 \
      pk_split(apa[2 * ks + 1][0], apa[2 * ks + 1][1], qa01h, qa01l);         \
      pk_split(apa[2 * ks + 1][2], apa[2 * ks + 1][3], qa23h, qa23l);         \
      pk_split(apb[2 * ks][0], apb[2 * ks][1], pb01h, pb01l);                 \
      pk_split(apb[2 * ks][2], apb[2 * ks][3], pb23h, pb23l);                 \
      pk_split(apb[2 * ks + 1][0], apb[2 * ks + 1][1], qb01h, qb01l);         \
      pk_split(apb[2 * ks + 1][2], apb[2 * ks + 1][3], qb23h, qb23l);         \
      const short8 bah = gather_frag(pa01h, pa23h, qa01h, qa23h, ad0, ad1, lowh); \
      const short8 bal = gather_frag(pa01l, pa23l, qa01l, qa23l, ad0, ad1, lowh); \
      const short8 bbh = gather_frag(pb01h, pb23h, qb01h, qb23h, ad0, ad1, lowh); \
      const short8 bbl = gather_frag(pb01l, pb23l, qb01l, qb23l, ad0, ad1, lowh); \
      _Pragma("unroll") for (int cm = 0; cm < 4; ++cm) {                      \
        short8 ah, al;                                                        \
        read_afragT(&(SCUR)[0], cm * 16 + l15, ks * 32 + q * 8, ah, al);      \
        npa[cm] = mfma16(ah, bah, npa[cm]);                                   \
        npa[cm] = mfma16(ah, bal, npa[cm]);                                   \
        npa[cm] = mfma16(al, bah, npa[cm]);                                   \
        npb[cm] = mfma16(ah, bbh, npb[cm]);                                   \
        npb[cm] = mfma16(ah, bbl, npb[cm]);                                   \
        npb[cm] = mfma16(al, bbh, npb[cm]);                                   \
      }                                                                       \
    }                                                                         \
    _Pragma("unroll") for (int cm = 0; cm < 4; ++cm) {                        \
      apa[cm] = npa[cm];                                                      \
      apb[cm] = npb[cm];                                                      \
    }                                                                         \
    if (more_) __syncthreads();                                               \
  } while (0)

__global__ __attribute__((amdgpu_flat_work_group_size(256, 256),
                          amdgpu_waves_per_eu(4, 4)))
void gdr_fold(const float* __restrict__ srcA, const float* __restrict__ srcB,
              float* __restrict__ dstA, float* __restrict__ dstB,
              int perChain, long chainBase, long idxBase, long elemStride,
              int nElem) {
  __shared__ float sA0[4096], sA1[4096];

  const int tid = threadIdx.x;
  const int lane = tid & 63, w = tid >> 6;
  const int q = lane >> 4, l15 = lane & 15;
  const int bh = blockIdx.x / perChain, id = blockIdx.x % perChain;
  const long e0 = (long)bh * chainBase + (long)id * idxBase;
  const int rowbase = (w * 16 + l15) * 64;
  const int ad0 = (l15 + ((lane >> 4) & 1) * 32) * 4;
  const int ad1 = ad0 + 64;
  const bool lowh = lane < 32;
  const int nS = nElem - 1;

  f32x4 apa[4], apb[4];
  {
    const float* At = srcA + (size_t)e0 * kTile;
    const float* Bt = srcB + (size_t)e0 * kTile;
#pragma unroll
    for (int cm = 0; cm < 4; ++cm) {
      apa[cm] = *reinterpret_cast<const f32x4*>(At + rowbase + cm * 16 + q * 4);
      apb[cm] = *reinterpret_cast<const f32x4*>(Bt + rowbase + cm * 16 + q * 4);
    }
  }

  f32x4 b0, b1, b2, b3;
  // prologue: stage element 1 -> sA0; preload B element 1.
  ISSUE_A(srcA + (size_t)(e0 + elemStride) * kTile, sA0);
  LOAD_B4(srcB + (size_t)(e0 + elemStride) * kTile);
  __syncthreads();

  int j = 0;
  while (true) {
    FOLD_STEP(j, sA0, sA1);
    if (++j >= nS) break;
    FOLD_STEP(j, sA1, sA0);
    if (++j >= nS) break;
  }

  float* pao = dstA + (size_t)blockIdx.x * kTile;
  float* pbo = dstB + (size_t)blockIdx.x * kTile;
#pragma unroll
  for (int cm = 0; cm < 4; ++cm) {
    *reinterpret_cast<f32x4*>(pao + rowbase + cm * 16 + q * 4) = apa[cm];
    *reinterpret_cast<f32x4*>(pbo + rowbase + cm * 16 + q * 4) = apb[cm];
  }
}

// ---------------- scan: apply nSteps elements, write states into out ----------------
// step I: issues element I+1 -> SNXT + B(I+1) at TOP, consumes b0..b3
// (B element I), computes with sA=SCUR (element I), writes state, barrier.
#define SCAN_STEP(I, SCUR, SNXT)                                              \
  do {                                                                        \
    const int i_ = (I);                                                       \
    const bool more_ = (i_ + 1 < nSteps);                                     \
    f32x4 nacc[4];                                                            \
    nacc[0] = b0; nacc[1] = b1; nacc[2] = b2; nacc[3] = b3;                   \
    if (more_) {                                                              \
      ISSUE_A(srcA + (size_t)(e0 + (long)(i_ + 1) * elemStride) * kTile, SNXT); \
      LOAD_B4(srcB + (size_t)(e0 + (long)(i_ + 1) * elemStride) * kTile);     \
      __builtin_amdgcn_sched_barrier(0);                                      \
    }                                                                         \
    _Pragma("unroll") for (int ks = 0; ks < 2; ++ks) {                        \
      u32 p01h, p01l, p23h, p23l, q01h, q01l, q23h, q23l;                     \
      pk_split(acc[2 * ks][0], acc[2 * ks][1], p01h, p01l);                   \
      pk_split(acc[2 * ks][2], acc[2 * ks][3], p23h, p23l);                   \
      pk_split(acc[2 * ks + 1][0], acc[2 * ks + 1][1], q01h, q01l);           \
      pk_split(acc[2 * ks + 1][2], acc[2 * ks + 1][3], q23h, q23l);           \
      const short8 bfh = gather_frag(p01h, p23h, q01h, q23h, ad0, ad1, lowh); \
      const short8 bfl = gather_frag(p01l, p23l, q01l, q23l, ad0, ad1, lowh); \
      _Pragma("unroll") for (int cm = 0; cm < 4; ++cm) {                      \
        short8 ah, al;                                                        \
        read_afragT(&(SCUR)[0], cm * 16 + l15, ks * 32 + q * 8, ah, al);      \
        nacc[cm] = mfma16(ah, bfh, nacc[cm]);                                 \
        nacc[cm] = mfma16(ah, bfl, nacc[cm]);                                 \
        nacc[cm] = mfma16(al, bfh, nacc[cm]);                                 \
      }                                                                       \
    }                                                                         \
    const int t_ = tBase + (i_ + 1) * tStep - 1;                              \
    float* o_ = out + ((size_t)t_ * kBH + bh) * kTile;                        \
    _Pragma("unroll") for (int cm = 0; cm < 4; ++cm) {                        \
      *reinterpret_cast<f32x4*>(o_ + rowbase + cm * 16 + q * 4) = nacc[cm];   \
      acc[cm] = nacc[cm];                                                     \
    }                                                                         \
    if (more_) __syncthreads();                                               \
  } while (0)

__global__ __attribute__((amdgpu_flat_work_group_size(256, 256),
                          amdgpu_waves_per_eu(4, 4)))
void gdr_scan(const float* __restrict__ srcA, const float* __restrict__ srcB,
              const float* __restrict__ S0, float* __restrict__ out,
              int perChain, long chainBase, long idxBase, long elemStride,
              int nSteps, int tbMul, int tStep) {
  __shared__ float sA0[4096], sA1[4096];

  const int tid = threadIdx.x;
  const int lane = tid & 63, w = tid >> 6;
  const int q = lane >> 4, l15 = lane & 15;
  const int bh = blockIdx.x / perChain, id = blockIdx.x % perChain;
  const long e0 = (long)bh * chainBase + (long)id * idxBase;
  const int tBase = id * tbMul;
  const int rowbase = (w * 16 + l15) * 64;
  const int ad0 = (l15 + ((lane >> 4) & 1) * 32) * 4;
  const int ad1 = ad0 + 64;
  const bool lowh = lane < 32;

  f32x4 acc[4];
  {
    const float* Sb = (tBase == 0) ? (S0 + (size_t)bh * kTile)
                                   : (out + ((size_t)(tBase - 1) * kBH + bh) * kTile);
#pragma unroll
    for (int cm = 0; cm < 4; ++cm)
      acc[cm] = *reinterpret_cast<const f32x4*>(Sb + rowbase + cm * 16 + q * 4);
  }

  f32x4 b0, b1, b2, b3;
  // prologue: stage element 0 -> sA0; preload B element 0.
  ISSUE_A(srcA + (size_t)e0 * kTile, sA0);
  LOAD_B4(srcB + (size_t)e0 * kTile);
  __syncthreads();

  int i = 0;
  while (true) {
    SCAN_STEP(i, sA0, sA1);
    if (++i >= nSteps) break;
    SCAN_STEP(i, sA1, sA0);
    if (++i >= nSteps) break;
  }
}

extern "C" void kernel_launch(void* const* d_in, const int* in_sizes, int n_in,
                              void* d_out, int out_size, void* d_ws, size_t ws_size,
                              hipStream_t stream) {
  const float* A  = (const float*)d_in[0];
  const float* Bm = (const float*)d_in[1];
  const float* S0 = (const float*)d_in[2];
  float* out = (float*)d_out;

  // workspace: PA[64*16], PB[64*16] tiles of 16 KB = 32 MB
  float* PA = (float*)d_ws;
  float* PB = PA + (size_t)kBH * kNC * kTile;

  // K1: chunk summaries. elements (ck*8+i)*64+bh, i=0..7
  gdr_fold<<<dim3(kBH * kNC), dim3(256), 0, stream>>>(
      A, Bm, PA, PB, kNC, 1L, (long)kCH * kBH, (long)kBH, kCH);
  // K2: scan 16 summaries (tiles bh*16+i); writes t = (i+1)*8-1 (7,15,...,127)
  gdr_scan<<<dim3(kBH), dim3(256), 0, stream>>>(
      PA, PB, S0, out, 1, (long)kNC, 0L, 1L, kNC, 0, kCH);
  // K3: in-chunk recurrence; elements (ck*8+i)*64+bh, start out[ck*8-1]/S0,
  //     writes t = ck*8+i for i=0..6
  gdr_scan<<<dim3(kBH * kNC), dim3(256), 0, stream>>>(
      A, Bm, S0, out, kNC, 1L, (long)kCH * kBH, (long)kBH, kCH - 1, kCH, 1);
}